// Round 1
// 259.446 us; speedup vs baseline: 1.1067x; 1.1067x over previous
//
#include <hip/hip_runtime.h>
#include <hip/hip_bf16.h>
#include <stdint.h>

// Problem constants (from reference)
#define IN_F   1024
#define OUT_F  1024
#define NLEAF  16
#define BATCH  4096

// GEMM C'[n, b] = sum_i W'[n,i] * Xb[b,i],  n = o*16+l  (n = C-tile ROW dim).
// R6: 256x256 tile, BK=32, 4-deep LDS ring (128 KB dynamic), 2 phases/K-tile
// with counted vmcnt(8) (never 0 mid-loop), raw s_barrier + setprio(1) around
// the MFMA clusters (T3+T4+T5 from the 8-phase template).  Tile t staged 3
// tiles ahead; end-of-tile vmcnt(8) keeps 2 tiles of loads in flight across
// barriers and only drains loads issued >=2 tiles (~1200 cyc) earlier.
#define KK      1024              // GEMM K = IN_F
#define NN      (OUT_F * NLEAF)   // 16384
#define BM      256               // n-tile
#define BN      256               // b-tile
#define BK      32
#define NKT     (KK / BK)         // 32 K-tiles
#define ABYTES  (BM * BK * 2)     // 16 KB per operand tile
#define SLICE   (2 * ABYTES)      // 32 KB (A+B) per ring slot; 4 slots = 128 KB
#define GS_PAD  257               // g-tile LDS row stride (conflict-free quads)

typedef __bf16 bf16x8 __attribute__((ext_vector_type(8)));
typedef float  f32x4  __attribute__((ext_vector_type(4)));

#define ASYNC_COPY16(gp, lp)                                                         \
  __builtin_amdgcn_global_load_lds((const __attribute__((address_space(1))) void*)(gp), \
                                   (__attribute__((address_space(3))) void*)(lp),       \
                                   16, 0, 0)

// ---------------------------------------------------------------------------
// Kernel 1: fused prep (UNCHANGED from R5).  Blocks [0,1024): transpose/pack
// pw -> W'.  Blocks [1024,2048): gating softmax + x->bf16 pack.
// ---------------------------------------------------------------------------
__global__ __launch_bounds__(256) void prep_kernel(
    const float* __restrict__ x, const float* __restrict__ gw,
    const float* __restrict__ gb, const float* __restrict__ pw,
    float* __restrict__ g, __hip_bfloat16* __restrict__ xb,
    __hip_bfloat16* __restrict__ W) {
  __shared__ __align__(16) __hip_bfloat16 lt[16 * 264];
  const int t = threadIdx.x;

  if (blockIdx.x < OUT_F) {
    // ---- pack_w path: W'[o*16+l, i] = bf16(pw[o,i,l]) via LDS transpose ----
    const int o = blockIdx.x;
    const float* src = pw + (size_t)o * (IN_F * NLEAF);
    for (int ch = 0; ch < 4; ++ch) {
      const float4* p = (const float4*)(src + ch * 4096 + t * 16);  // i=t, 16 l
      const float4 v0 = p[0], v1 = p[1], v2 = p[2], v3 = p[3];
      if (ch) __syncthreads();   // prev readout done before overwriting lt
      lt[ 0 * 264 + t] = __float2bfloat16(v0.x);
      lt[ 1 * 264 + t] = __float2bfloat16(v0.y);
      lt[ 2 * 264 + t] = __float2bfloat16(v0.z);
      lt[ 3 * 264 + t] = __float2bfloat16(v0.w);
      lt[ 4 * 264 + t] = __float2bfloat16(v1.x);
      lt[ 5 * 264 + t] = __float2bfloat16(v1.y);
      lt[ 6 * 264 + t] = __float2bfloat16(v1.z);
      lt[ 7 * 264 + t] = __float2bfloat16(v1.w);
      lt[ 8 * 264 + t] = __float2bfloat16(v2.x);
      lt[ 9 * 264 + t] = __float2bfloat16(v2.y);
      lt[10 * 264 + t] = __float2bfloat16(v2.z);
      lt[11 * 264 + t] = __float2bfloat16(v2.w);
      lt[12 * 264 + t] = __float2bfloat16(v3.x);
      lt[13 * 264 + t] = __float2bfloat16(v3.y);
      lt[14 * 264 + t] = __float2bfloat16(v3.z);
      lt[15 * 264 + t] = __float2bfloat16(v3.w);
      __syncthreads();
#pragma unroll
      for (int jj = 0; jj < 2; ++jj) {
        const int u = t + 256 * jj;        // 512 uint4 per chunk
        const int l = u >> 5;
        const int i8 = (u & 31) * 8;
        *(uint4*)(W + ((size_t)o * NLEAF + l) * KK + ch * 256 + i8) =
            *(const uint4*)(lt + l * 264 + i8);
      }
    }
  } else {
    // ---- gate + pack_x path ----
    const int blk  = blockIdx.x - OUT_F;
    const int lane = t & 63;
    const int wv   = t >> 6;
    const int b    = blk * 4 + wv;
    const int i4   = lane >> 4;
    const int l    = lane & 15;

    const float* xrow = x + (size_t)b * IN_F;
    float acc = 0.f;
#pragma unroll 8
    for (int k = 0; k < IN_F / 4; ++k) {
      const float xv = xrow[k * 4 + i4];          // same addr per 16-group (L1)
      const float wvv = gw[k * 64 + lane];        // coalesced
      acc = fmaf(xv, wvv, acc);
    }
    acc += __shfl_xor(acc, 16);
    acc += __shfl_xor(acc, 32);
    float logit = acc + gb[l];
    float m = logit;
#pragma unroll
    for (int off = 8; off > 0; off >>= 1) m = fmaxf(m, __shfl_xor(m, off));
    float e = __expf(logit - m);
    float s = e;
#pragma unroll
    for (int off = 8; off > 0; off >>= 1) s += __shfl_xor(s, off);
    if (lane < NLEAF) g[b * NLEAF + l] = e / s;

    const float* xblk = x + (size_t)blk * 4 * IN_F;
    __hip_bfloat16* xbblk = xb + (size_t)blk * 4 * IN_F;
#pragma unroll
    for (int j = 0; j < 2; ++j) {
      const int f = (t + 256 * j) * 8;
      const float4 a0 = *(const float4*)(xblk + f);
      const float4 a1 = *(const float4*)(xblk + f + 4);
      __align__(16) __hip_bfloat16 tmp[8];
      tmp[0] = __float2bfloat16(a0.x); tmp[1] = __float2bfloat16(a0.y);
      tmp[2] = __float2bfloat16(a0.z); tmp[3] = __float2bfloat16(a0.w);
      tmp[4] = __float2bfloat16(a1.x); tmp[5] = __float2bfloat16(a1.y);
      tmp[6] = __float2bfloat16(a1.z); tmp[7] = __float2bfloat16(a1.w);
      *(uint4*)(xbblk + f) = *(const uint4*)tmp;
    }
  }
}

// ---------------------------------------------------------------------------
// Kernel 2: bf16 MFMA GEMM, deep-pipelined 256x256 tile.
// 512 threads = 8 waves (2 n-dir x 4 b-dir); per-wave output 128x64;
// acc[mi][ni][r] = C'[n = n0 + wr*128 + mi*16 + quad*4 + r][b = b0 + wc*64 +
// ni*16 + r16]; l = quad*4+r, o = n/16.  Staging keeps R5's K-slot XOR
// swizzle (verified conflict-free fragment reads): chunk c -> row c>>2,
// phys slot c&3, GLOBAL slot (c&3)^((c>>3)&3); frag read slot = quad^swz.
// ---------------------------------------------------------------------------
#define STAGE_A(tt)                                                  \
  do {                                                               \
    char* _d = smem + (((tt) & 3) * SLICE);                          \
    const __hip_bfloat16* _s = aG + (long)(tt) * BK;                 \
    ASYNC_COPY16(_s + gOff0, _d + c0 * 16);                          \
    ASYNC_COPY16(_s + gOff1, _d + c1 * 16);                          \
  } while (0)

#define STAGE_B(tt)                                                  \
  do {                                                               \
    char* _d = smem + (((tt) & 3) * SLICE) + ABYTES;                 \
    const __hip_bfloat16* _s = bG + (long)(tt) * BK;                 \
    ASYNC_COPY16(_s + gOff0, _d + c0 * 16);                          \
    ASYNC_COPY16(_s + gOff1, _d + c1 * 16);                          \
  } while (0)

// One K-tile: phase A = {ds_read af0-3,bf0-3 | stage A(tt+3) | bar |
// lgkmcnt(0) | 16 MFMA} ; phase B = {ds_read af4-7 | stage B(tt+3) |
// counted vmcnt | bar | lgkmcnt(0) | 16 MFMA}.  TAILVM never 0 mid-loop.
#define TILE_ITER(tt, DO_STAGE, TAILVM)                                        \
  do {                                                                         \
    const __hip_bfloat16* As =                                                 \
        (const __hip_bfloat16*)(smem + ((tt) & 3) * SLICE);                    \
    const __hip_bfloat16* Bs =                                                 \
        (const __hip_bfloat16*)(smem + ((tt) & 3) * SLICE + ABYTES);           \
    bf16x8 af0, af1, af2, af3, bv0, bv1, bv2, bv3;                             \
    af0 = *(const bf16x8*)(As + ((wr * 128 +  0 + r16) * 4 + (quad ^ swz)) * 8); \
    af1 = *(const bf16x8*)(As + ((wr * 128 + 16 + r16) * 4 + (quad ^ swz)) * 8); \
    af2 = *(const bf16x8*)(As + ((wr * 128 + 32 + r16) * 4 + (quad ^ swz)) * 8); \
    af3 = *(const bf16x8*)(As + ((wr * 128 + 48 + r16) * 4 + (quad ^ swz)) * 8); \
    bv0 = *(const bf16x8*)(Bs + ((wc * 64 +  0 + r16) * 4 + (quad ^ swz)) * 8);  \
    bv1 = *(const bf16x8*)(Bs + ((wc * 64 + 16 + r16) * 4 + (quad ^ swz)) * 8);  \
    bv2 = *(const bf16x8*)(Bs + ((wc * 64 + 32 + r16) * 4 + (quad ^ swz)) * 8);  \
    bv3 = *(const bf16x8*)(Bs + ((wc * 64 + 48 + r16) * 4 + (quad ^ swz)) * 8);  \
    if (DO_STAGE) STAGE_A((tt) + 3);                                           \
    __builtin_amdgcn_s_barrier();                                              \
    asm volatile("s_waitcnt lgkmcnt(0)" ::: "memory");                         \
    __builtin_amdgcn_sched_barrier(0);                                         \
    __builtin_amdgcn_s_setprio(1);                                             \
    acc[0][0] = __builtin_amdgcn_mfma_f32_16x16x32_bf16(af0, bv0, acc[0][0], 0, 0, 0); \
    acc[0][1] = __builtin_amdgcn_mfma_f32_16x16x32_bf16(af0, bv1, acc[0][1], 0, 0, 0); \
    acc[0][2] = __builtin_amdgcn_mfma_f32_16x16x32_bf16(af0, bv2, acc[0][2], 0, 0, 0); \
    acc[0][3] = __builtin_amdgcn_mfma_f32_16x16x32_bf16(af0, bv3, acc[0][3], 0, 0, 0); \
    acc[1][0] = __builtin_amdgcn_mfma_f32_16x16x32_bf16(af1, bv0, acc[1][0], 0, 0, 0); \
    acc[1][1] = __builtin_amdgcn_mfma_f32_16x16x32_bf16(af1, bv1, acc[1][1], 0, 0, 0); \
    acc[1][2] = __builtin_amdgcn_mfma_f32_16x16x32_bf16(af1, bv2, acc[1][2], 0, 0, 0); \
    acc[1][3] = __builtin_amdgcn_mfma_f32_16x16x32_bf16(af1, bv3, acc[1][3], 0, 0, 0); \
    acc[2][0] = __builtin_amdgcn_mfma_f32_16x16x32_bf16(af2, bv0, acc[2][0], 0, 0, 0); \
    acc[2][1] = __builtin_amdgcn_mfma_f32_16x16x32_bf16(af2, bv1, acc[2][1], 0, 0, 0); \
    acc[2][2] = __builtin_amdgcn_mfma_f32_16x16x32_bf16(af2, bv2, acc[2][2], 0, 0, 0); \
    acc[2][3] = __builtin_amdgcn_mfma_f32_16x16x32_bf16(af2, bv3, acc[2][3], 0, 0, 0); \
    acc[3][0] = __builtin_amdgcn_mfma_f32_16x16x32_bf16(af3, bv0, acc[3][0], 0, 0, 0); \
    acc[3][1] = __builtin_amdgcn_mfma_f32_16x16x32_bf16(af3, bv1, acc[3][1], 0, 0, 0); \
    acc[3][2] = __builtin_amdgcn_mfma_f32_16x16x32_bf16(af3, bv2, acc[3][2], 0, 0, 0); \
    acc[3][3] = __builtin_amdgcn_mfma_f32_16x16x32_bf16(af3, bv3, acc[3][3], 0, 0, 0); \
    __builtin_amdgcn_s_setprio(0);                                             \
    __builtin_amdgcn_s_barrier();                                              \
    af0 = *(const bf16x8*)(As + ((wr * 128 +  64 + r16) * 4 + (quad ^ swz)) * 8); \
    af1 = *(const bf16x8*)(As + ((wr * 128 +  80 + r16) * 4 + (quad ^ swz)) * 8); \
    af2 = *(const bf16x8*)(As + ((wr * 128 +  96 + r16) * 4 + (quad ^ swz)) * 8); \
    af3 = *(const bf16x8*)(As + ((wr * 128 + 112 + r16) * 4 + (quad ^ swz)) * 8); \
    if (DO_STAGE) STAGE_B((tt) + 3);                                           \
    TAILVM;                                                                    \
    __builtin_amdgcn_s_barrier();                                              \
    asm volatile("s_waitcnt lgkmcnt(0)" ::: "memory");                         \
    __builtin_amdgcn_sched_barrier(0);                                         \
    __builtin_amdgcn_s_setprio(1);                                             \
    acc[4][0] = __builtin_amdgcn_mfma_f32_16x16x32_bf16(af0, bv0, acc[4][0], 0, 0, 0); \
    acc[4][1] = __builtin_amdgcn_mfma_f32_16x16x32_bf16(af0, bv1, acc[4][1], 0, 0, 0); \
    acc[4][2] = __builtin_amdgcn_mfma_f32_16x16x32_bf16(af0, bv2, acc[4][2], 0, 0, 0); \
    acc[4][3] = __builtin_amdgcn_mfma_f32_16x16x32_bf16(af0, bv3, acc[4][3], 0, 0, 0); \
    acc[5][0] = __builtin_amdgcn_mfma_f32_16x16x32_bf16(af1, bv0, acc[5][0], 0, 0, 0); \
    acc[5][1] = __builtin_amdgcn_mfma_f32_16x16x32_bf16(af1, bv1, acc[5][1], 0, 0, 0); \
    acc[5][2] = __builtin_amdgcn_mfma_f32_16x16x32_bf16(af1, bv2, acc[5][2], 0, 0, 0); \
    acc[5][3] = __builtin_amdgcn_mfma_f32_16x16x32_bf16(af1, bv3, acc[5][3], 0, 0, 0); \
    acc[6][0] = __builtin_amdgcn_mfma_f32_16x16x32_bf16(af2, bv0, acc[6][0], 0, 0, 0); \
    acc[6][1] = __builtin_amdgcn_mfma_f32_16x16x32_bf16(af2, bv1, acc[6][1], 0, 0, 0); \
    acc[6][2] = __builtin_amdgcn_mfma_f32_16x16x32_bf16(af2, bv2, acc[6][2], 0, 0, 0); \
    acc[6][3] = __builtin_amdgcn_mfma_f32_16x16x32_bf16(af2, bv3, acc[6][3], 0, 0, 0); \
    acc[7][0] = __builtin_amdgcn_mfma_f32_16x16x32_bf16(af3, bv0, acc[7][0], 0, 0, 0); \
    acc[7][1] = __builtin_amdgcn_mfma_f32_16x16x32_bf16(af3, bv1, acc[7][1], 0, 0, 0); \
    acc[7][2] = __builtin_amdgcn_mfma_f32_16x16x32_bf16(af3, bv2, acc[7][2], 0, 0, 0); \
    acc[7][3] = __builtin_amdgcn_mfma_f32_16x16x32_bf16(af3, bv3, acc[7][3], 0, 0, 0); \
    __builtin_amdgcn_s_setprio(0);                                             \
    __builtin_amdgcn_s_barrier();                                              \
  } while (0)

__global__ __launch_bounds__(512, 2) void gemm_kernel(
    const __hip_bfloat16* __restrict__ Xb,  // [BATCH, KK]
    const __hip_bfloat16* __restrict__ W,   // [NN, KK], row n = o*16+l
    const float* __restrict__ g,            // [BATCH, NLEAF]
    const float* __restrict__ pb,           // [OUT_F, NLEAF]
    float* __restrict__ out) {              // [BATCH, OUT_F]
  extern __shared__ __align__(16) char smem[];  // 4 ring slots x 32 KB

  const int t    = threadIdx.x;
  const int lane = t & 63;
  const int w    = t >> 6;
  const int quad = lane >> 4;
  const int r16  = lane & 15;
  const int wr   = w >> 2;   // 0..1: A rows wr*128
  const int wc   = w & 3;    // 0..3: B rows (b-dir) wc*64
  const int swz  = (r16 >> 1) & 3;

  const int b0 = blockIdx.x * BN;
  const int n0 = blockIdx.y * BM;

  const __hip_bfloat16* aG = W  + (long)n0 * KK;
  const __hip_bfloat16* bG = Xb + (long)b0 * KK;

  // staging: 1024 16-B chunks per operand tile; chunk c -> row c>>2,
  // LDS phys slot c&3, GLOBAL slot (c&3)^((c>>3)&3)
  const int  c0 = t, c1 = t + 512;
  const long gOff0 = (long)(c0 >> 2) * KK + (long)(((c0 & 3) ^ ((c0 >> 3) & 3)) * 8);
  const long gOff1 = (long)(c1 >> 2) * KK + (long)(((c1 & 3) ^ ((c1 >> 3) & 3)) * 8);

  f32x4 acc[8][4] = {};

  // Prologue: fill 3 tiles of the ring; wait so tile 0 (oldest 4 loads) landed.
  STAGE_A(0); STAGE_B(0);
  STAGE_A(1); STAGE_B(1);
  STAGE_A(2); STAGE_B(2);
  asm volatile("s_waitcnt vmcnt(8)" ::: "memory");
  __builtin_amdgcn_s_barrier();

  // Steady state: end-of-tile vmcnt(8) leaves the 2 newest tiles in flight;
  // drained loads were issued >=2 tiles (~1200 cyc) earlier -> wait is free.
  for (int tt = 0; tt < NKT - 3; ++tt)
    TILE_ITER(tt, 1, asm volatile("s_waitcnt vmcnt(8)" ::: "memory"));
  TILE_ITER(NKT - 3, 0, asm volatile("s_waitcnt vmcnt(4)" ::: "memory"));
  TILE_ITER(NKT - 2, 0, asm volatile("s_waitcnt vmcnt(0)" ::: "memory"));
  TILE_ITER(NKT - 1, 0, (void)0);

  // ---- stage g (transposed, padded) and pb into the (dead) ring LDS ----
  float* gs  = (float*)smem;                       // [16][GS_PAD]
  float* pbs = (float*)(smem + 16 * GS_PAD * 4);   // [256]
#pragma unroll
  for (int j = 0; j < 8; ++j) {
    const int f = t + 512 * j;                     // 0..4095
    gs[(f & 15) * GS_PAD + (f >> 4)] = g[b0 * NLEAF + f];
  }
  if (t < 256) pbs[t] = pb[(n0 >> 4) * NLEAF + t]; // o0 = n0/16; pb flat [o,l]
  __syncthreads();

  // ---- fused gated-reduction epilogue ----
  const int oBase = (n0 >> 4) + wr * 8;            // 8 consecutive o's (mi)
#pragma unroll
  for (int ni = 0; ni < 4; ++ni) {
    const int bl = wc * 64 + ni * 16 + r16;
    float gv[4];
#pragma unroll
    for (int r = 0; r < 4; ++r) gv[r] = gs[(quad * 4 + r) * GS_PAD + bl];
    float rv[8];
#pragma unroll
    for (int mi = 0; mi < 8; ++mi) {
      float v = 0.f;
#pragma unroll
      for (int r = 0; r < 4; ++r)
        v = fmaf(acc[mi][ni][r] + pbs[(wr * 8 + mi) * NLEAF + quad * 4 + r],
                 gv[r], v);
      v += __shfl_xor(v, 16);
      v += __shfl_xor(v, 32);                      // sum over quads -> sum_l
      rv[mi] = v;
    }
    if (quad == 0) {
      *(float4*)(out + (long)(b0 + bl) * OUT_F + oBase) =
          make_float4(rv[0], rv[1], rv[2], rv[3]);
      *(float4*)(out + (long)(b0 + bl) * OUT_F + oBase + 4) =
          make_float4(rv[4], rv[5], rv[6], rv[7]);
    }
  }
}

// ---------------------------------------------------------------------------
// Fallback (ws too small for packed buffers): slow but correct fp32 path.
// ---------------------------------------------------------------------------
__global__ __launch_bounds__(256) void gate_kernel_fb(
    const float* __restrict__ x, const float* __restrict__ gw,
    const float* __restrict__ gb, float* __restrict__ g) {
  const int lane = threadIdx.x & 63;
  const int wv   = threadIdx.x >> 6;
  const int b    = blockIdx.x * 4 + wv;
  const int i4   = lane >> 4;
  const int l    = lane & 15;
  const float* xrow = x + (size_t)b * IN_F;
  float acc = 0.f;
  for (int k = 0; k < IN_F / 4; ++k)
    acc = fmaf(xrow[k * 4 + i4], gw[k * 64 + lane], acc);
  acc += __shfl_xor(acc, 16);
  acc += __shfl_xor(acc, 32);
  float logit = acc + gb[l];
  float m = logit;
  for (int off = 8; off > 0; off >>= 1) m = fmaxf(m, __shfl_xor(m, off));
  float e = __expf(logit - m);
  float s = e;
  for (int off = 8; off > 0; off >>= 1) s += __shfl_xor(s, off);
  if (lane < NLEAF) g[b * NLEAF + l] = e / s;
}

__global__ __launch_bounds__(256) void fallback_kernel(
    const float* __restrict__ x, const float* __restrict__ pw,
    const float* __restrict__ pb, const float* __restrict__ g,
    float* __restrict__ out) {
  const int b = blockIdx.x;
  __shared__ float xs[IN_F];
  __shared__ float gsl[NLEAF];
  const int t = threadIdx.x;
  for (int j = t; j < IN_F; j += 256) xs[j] = x[(long)b * IN_F + j];
  if (t < NLEAF) gsl[t] = g[b * NLEAF + t];
  __syncthreads();
  for (int o = t; o < OUT_F; o += 256) {
    const float* pwo = pw + (long)o * (IN_F * NLEAF);
    float acc = 0.f;
    for (int i = 0; i < IN_F; ++i) {
      const float xv = xs[i];
      float wsum = 0.f;
#pragma unroll
      for (int l = 0; l < NLEAF; ++l) wsum += gsl[l] * pwo[i * NLEAF + l];
      acc += xv * wsum;
    }
    float bias = 0.f;
#pragma unroll
    for (int l = 0; l < NLEAF; ++l) bias += gsl[l] * pb[o * NLEAF + l];
    out[(long)b * OUT_F + o] = acc + bias;
  }
}

extern "C" void kernel_launch(void* const* d_in, const int* in_sizes, int n_in,
                              void* d_out, int out_size, void* d_ws, size_t ws_size,
                              hipStream_t stream) {
  const float* x  = (const float*)d_in[0];  // [4096,1024]
  const float* gw = (const float*)d_in[1];  // [1024,16]
  const float* gb = (const float*)d_in[2];  // [16]
  const float* pw = (const float*)d_in[3];  // [1024,1024,16]
  const float* pb = (const float*)d_in[4];  // [1024,16]
  float* out = (float*)d_out;               // [4096,1024]

  const size_t w_bytes  = (size_t)NN * KK * sizeof(__hip_bfloat16);    // 33.6 MB
  const size_t xb_bytes = (size_t)BATCH * KK * sizeof(__hip_bfloat16); //  8.4 MB
  const size_t g_bytes  = (size_t)BATCH * NLEAF * sizeof(float);       //  0.26 MB

  if (ws_size >= w_bytes + xb_bytes + g_bytes) {
    __hip_bfloat16* W  = (__hip_bfloat16*)d_ws;
    __hip_bfloat16* xb = (__hip_bfloat16*)((char*)d_ws + w_bytes);
    float*          g  = (float*)((char*)d_ws + w_bytes + xb_bytes);

    static int attr_done = 0;
    if (!attr_done) {
      // 128 KB dynamic LDS (> 64 KB default cap); gfx950 has 160 KB/CU.
      (void)hipFuncSetAttribute((const void*)gemm_kernel,
                                hipFuncAttributeMaxDynamicSharedMemorySize,
                                4 * SLICE);
      attr_done = 1;
    }

    prep_kernel<<<OUT_F + BATCH / 4, 256, 0, stream>>>(x, gw, gb, pw, g, xb, W);
    gemm_kernel<<<dim3(BATCH / BN, NN / BM), 512, 4 * SLICE, stream>>>(
        xb, W, g, pb, out);
  } else {
    float* g = (float*)d_ws;  // needs only 256 KB
    gate_kernel_fb<<<BATCH / 4, 256, 0, stream>>>(x, gw, gb, g);
    fallback_kernel<<<BATCH, 256, 0, stream>>>(x, pw, pb, g, out);
  }
}